// Round 1
// 198.978 us; speedup vs baseline: 1.1734x; 1.1734x over previous
//
#include <hip/hip_runtime.h>
#include <math.h>
#include <float.h>

#define BN 32
#define CH 3
#define HH 512
#define WW 512
#define NP 4
#define EPS 128
#define HALF 64
#define MARGIN 32

#define NT 4096                                  // 64x64 grid of 8x8 tiles per map
#define PATCH_ELEMS (BN * NP * CH * EPS * EPS)   // 6291456
#define F4_PER_MAP (NP * CH * EPS * EPS / 4)     // 49152
#define NSLICE 16
#define F4_PER_SLICE (F4_PER_MAP / NSLICE)       // 3072 = 3 * 1024
#define K2_NTHR 1024
#define K2_NBLK (BN * NSLICE)                    // 512
#define K1_NTHR 256
#define K1_NBLK (BN * NT / K1_NTHR)              // 512

// ============ K1: per-tile (max,argmax) for all maps, computed ONCE =========
// 131072 threads, one 8x8 tile each. Coalesced: a wave covers one full tile
// row (64 tiles * 32B per r-step = 2KB contiguous). Writes 1MB (val,idx) to ws.
__global__ __launch_bounds__(K1_NTHR)
void tile_scan(const float* __restrict__ umaps, float2* __restrict__ tiles)
{
    const int g  = blockIdx.x * K1_NTHR + threadIdx.x;
    const int b  = g >> 12;                      // map
    const int t  = g & (NT - 1);                 // tile within map
    const int tx = t & 63, ty = t >> 6;
    const float* __restrict__ um = umaps + (size_t)b * HH * WW;
    const int x0 = tx << 3, y0 = ty << 3;
    float bv = -INFINITY; int bi = 0x7fffffff;
    #pragma unroll
    for (int r = 0; r < 8; ++r) {
        const int rowbase = (y0 + r) * WW + x0;
        const float4 a = *(const float4*)(um + rowbase);
        const float4 c = *(const float4*)(um + rowbase + 4);
        if (a.x > bv) { bv = a.x; bi = rowbase + 0; }
        if (a.y > bv) { bv = a.y; bi = rowbase + 1; }
        if (a.z > bv) { bv = a.z; bi = rowbase + 2; }
        if (a.w > bv) { bv = a.w; bi = rowbase + 3; }
        if (c.x > bv) { bv = c.x; bi = rowbase + 4; }
        if (c.y > bv) { bv = c.y; bi = rowbase + 5; }
        if (c.z > bv) { bv = c.z; bi = rowbase + 6; }
        if (c.w > bv) { bv = c.w; bi = rowbase + 7; }
    }
    tiles[g] = make_float2(bv, __int_as_float(bi));
}

// ============ K2: redundant greedy selection from tile cache + extraction ===
// 512 blocks: b = blk&31, slice = blk>>5 (16 slices/map; map b -> XCD b&7).
// Deterministic selection => all 16 blocks of a map agree. Phase 1 is now a
// 32KB coalesced load; rescan uses 8-bit row masks and compacted tile->tid
// assignment (all lanes of the ~10 active waves busy).
__global__ __launch_bounds__(K2_NTHR)
void select_extract(const float* __restrict__ images,
                    const float* __restrict__ umaps,
                    const float2* __restrict__ tiles,
                    float* __restrict__ out)
{
    const int tid   = threadIdx.x;
    const int lane  = tid & 63;
    const int wave  = tid >> 6;
    const int b     = blockIdx.x & (BN - 1);
    const int slice = blockIdx.x >> 5;
    const float* __restrict__ um = umaps + (size_t)b * HH * WW;
    float* coords_out = out + PATCH_ELEMS;

    __shared__ float2 tvi[NT];       // (val, bitcast idx) per tile
    __shared__ int   boxes[NP][4];   // margin-expanded, clipped ex1,ex2,ey1,ey2
    __shared__ float rv[16];
    __shared__ int   ri[16];
    __shared__ int   sx1[NP], sy1[NP];

    // ---- load own map's tile cache from K1 output (32KB, coalesced) --------
    {
        const float4* __restrict__ src = (const float4*)(tiles + (size_t)b * NT);
        float4* dst = (float4*)tvi;
        dst[tid]        = src[tid];
        dst[tid + 1024] = src[tid + 1024];
    }
    if (tid < NP) {   // boxes start empty => mask tests inert
        boxes[tid][0] = 0; boxes[tid][1] = 0; boxes[tid][2] = 0; boxes[tid][3] = 0;
    }
    __syncthreads();

    // ---- greedy selection --------------------------------------------------
    for (int k = 0; k < NP; ++k) {
        // block argmax over 4096 tile entries
        float bv = -INFINITY; int bi = 0x7fffffff;
        #pragma unroll
        for (int i = 0; i < 4; ++i) {
            const float2 e = tvi[tid + (i << 10)];
            const float v = e.x; const int x = __float_as_int(e.y);
            if (v > bv || (v == bv && x < bi)) { bv = v; bi = x; }
        }
        #pragma unroll
        for (int off = 32; off > 0; off >>= 1) {
            float ov = __shfl_down(bv, off);
            int   oi = __shfl_down(bi, off);
            if (ov > bv || (ov == bv && oi < bi)) { bv = ov; bi = oi; }
        }
        if (lane == 0) { rv[wave] = bv; ri[wave] = bi; }
        __syncthreads();

        if (tid == 0) {
            bv = rv[0]; bi = ri[0];
            #pragma unroll
            for (int w = 1; w < 16; ++w)
                if (rv[w] > bv || (rv[w] == bv && ri[w] < bi)) { bv = rv[w]; bi = ri[w]; }
            const int yc = bi >> 9, xc = bi & 511;
            int x1 = max(0, xc - HALF), x2 = min(WW, xc + HALF);
            int y1 = max(0, yc - HALF), y2 = min(HH, yc + HALF);
            if (x2 - x1 < EPS) { if (x1 == 0) x2 = EPS; else x1 = x2 - EPS; }
            if (y2 - y1 < EPS) { if (y1 == 0) y2 = EPS; else y1 = y2 - EPS; }
            boxes[k][0] = max(x1 - MARGIN, 0);
            boxes[k][1] = min(x2 + MARGIN, WW);
            boxes[k][2] = max(y1 - MARGIN, 0);
            boxes[k][3] = min(y2 + MARGIN, HH);
            sx1[k] = x1; sy1[k] = y1;

            if (slice == 0) {   // one writer per map
                const int o = (b * NP + k) * 4;
                coords_out[o + 0] = (float)x1;
                coords_out[o + 1] = (float)y1;
                coords_out[o + 2] = (float)x2;
                coords_out[o + 3] = (float)y2;
            }
        }
        __syncthreads();

        if (k == NP - 1) break;

        // ---- compacted rescan of tiles overlapping new box k ----
        const int ex1 = boxes[k][0], ex2 = boxes[k][1];
        const int ey1 = boxes[k][2], ey2 = boxes[k][3];
        const int tx1 = ex1 >> 3, tx2 = (ex2 - 1) >> 3;
        const int ty1 = ey1 >> 3, ty2 = (ey2 - 1) >> 3;
        const int wt  = tx2 - tx1 + 1;
        const int nt2 = wt * (ty2 - ty1 + 1);      // <= 625
        if (tid < nt2) {
            const int tx = tx1 + tid % wt;
            const int ty = ty1 + tid / wt;
            const int t  = (ty << 6) + tx;
            const int X1 = tx << 3, Y1 = ty << 3;
            if (X1 >= ex1 && X1 + 8 <= ex2 && Y1 >= ey1 && Y1 + 8 <= ey2) {
                // fully inside new box
                tvi[t] = make_float2(-INFINITY, __int_as_float(0x7fffffff));
            } else {
                // per-box 8-bit x-mask + y-range (empty boxes give xm=0/empty range)
                unsigned xm[NP]; int byl[NP], byh[NP];
                #pragma unroll
                for (int j = 0; j < NP; ++j) {
                    const int lo = min(max(boxes[j][0] - X1, 0), 8);
                    const int hi = min(max(boxes[j][1] - X1, 0), 8);
                    xm[j]  = (0xFFu << lo) & (0xFFu >> (8 - hi));
                    byl[j] = boxes[j][2]; byh[j] = boxes[j][3];
                }
                float nv = -INFINITY; int ni = 0x7fffffff;
                #pragma unroll
                for (int r = 0; r < 8; ++r) {
                    const int y = Y1 + r;
                    unsigned m8 = 0;
                    #pragma unroll
                    for (int j = 0; j < NP; ++j)
                        m8 |= (y >= byl[j] && y < byh[j]) ? xm[j] : 0u;
                    const int rowbase = y * WW + X1;
                    const float4 a = *(const float4*)(um + rowbase);
                    const float4 c = *(const float4*)(um + rowbase + 4);
                    const float vals[8] = {a.x, a.y, a.z, a.w, c.x, c.y, c.z, c.w};
                    #pragma unroll
                    for (int j2 = 0; j2 < 8; ++j2) {
                        if (!((m8 >> j2) & 1u) && vals[j2] > nv) { nv = vals[j2]; ni = rowbase + j2; }
                    }
                }
                tvi[t] = make_float2(nv, __int_as_float(ni));
            }
        }
        __syncthreads();
    }

    // ---- extraction: own map's 1/16 slice ----------------------------------
    float4* __restrict__ out4 = (float4*)out;
    #pragma unroll
    for (int it = 0; it < 3; ++it) {
        const int il  = slice * F4_PER_SLICE + (it << 10) + tid;  // within-map f4 idx
        const int nc  = il >> 12;            // (n,c) plane, 0..11
        const int n   = nc / 3;
        const int c   = nc - n * 3;
        const int py  = (il >> 5) & 127;
        const int px0 = (il & 31) << 2;

        const int x1 = sx1[n], y1 = sy1[n];
        const float* __restrict__ src =
            images + (((size_t)b * CH + c) * HH + (y1 + py)) * WW + x1 + px0;
        out4[(size_t)b * F4_PER_MAP + il] = make_float4(src[0], src[1], src[2], src[3]);
    }
}

extern "C" void kernel_launch(void* const* d_in, const int* in_sizes, int n_in,
                              void* d_out, int out_size, void* d_ws, size_t ws_size,
                              hipStream_t stream) {
    const float* images = (const float*)d_in[0];
    const float* umaps  = (const float*)d_in[1];
    float* out          = (float*)d_out;
    float2* tiles       = (float2*)d_ws;        // 32 maps * 4096 tiles * 8B = 1MB

    tile_scan<<<K1_NBLK, K1_NTHR, 0, stream>>>(umaps, tiles);
    select_extract<<<K2_NBLK, K2_NTHR, 0, stream>>>(images, umaps, tiles, out);
}

// Round 2
// 188.246 us; speedup vs baseline: 1.2403x; 1.0570x over previous
//
#include <hip/hip_runtime.h>
#include <math.h>
#include <float.h>

#define BN 32
#define CH 3
#define HH 512
#define WW 512
#define NP 4
#define EPS 128
#define HALF 64
#define MARGIN 32

#define NT 4096                                  // 64x64 grid of 8x8 tiles per map
#define PATCH_ELEMS (BN * NP * CH * EPS * EPS)   // 6291456
#define F4_PER_MAP (NP * CH * EPS * EPS / 4)     // 49152 (12 planes * 4096 f4)
#define NSLICE 16
#define F4_PER_SLICE (F4_PER_MAP / NSLICE)       // 3072
#define K1_NTHR 256
#define K1_NBLK (BN * NT / K1_NTHR)              // 512
#define EX_NBLK (BN * NSLICE)                    // 512

// ============ K1: per-tile (max,argmax) for all maps, computed ONCE =========
__global__ __launch_bounds__(K1_NTHR)
void tile_scan(const float* __restrict__ umaps, float2* __restrict__ tiles)
{
    const int g  = blockIdx.x * K1_NTHR + threadIdx.x;
    const int b  = g >> 12;                      // map
    const int t  = g & (NT - 1);                 // tile within map
    const int tx = t & 63, ty = t >> 6;
    const float* __restrict__ um = umaps + (size_t)b * HH * WW;
    const int x0 = tx << 3, y0 = ty << 3;
    float bv = -INFINITY; int bi = 0x7fffffff;
    #pragma unroll
    for (int r = 0; r < 8; ++r) {
        const int rowbase = (y0 + r) * WW + x0;
        const float4 a = *(const float4*)(um + rowbase);
        const float4 c = *(const float4*)(um + rowbase + 4);
        if (a.x > bv) { bv = a.x; bi = rowbase + 0; }
        if (a.y > bv) { bv = a.y; bi = rowbase + 1; }
        if (a.z > bv) { bv = a.z; bi = rowbase + 2; }
        if (a.w > bv) { bv = a.w; bi = rowbase + 3; }
        if (c.x > bv) { bv = c.x; bi = rowbase + 4; }
        if (c.y > bv) { bv = c.y; bi = rowbase + 5; }
        if (c.z > bv) { bv = c.z; bi = rowbase + 6; }
        if (c.w > bv) { bv = c.w; bi = rowbase + 7; }
    }
    tiles[g] = make_float2(bv, __int_as_float(bi));
}

// ============ K2: greedy selection, ONCE per map (32 blocks) ================
// Writes coords (float) to out tail and (x1,y1) per patch to ws sxy.
__global__ __launch_bounds__(1024)
void select_k(const float* __restrict__ umaps,
              const float2* __restrict__ tiles,
              float* __restrict__ out,
              int2* __restrict__ sxy)
{
    const int tid   = threadIdx.x;
    const int lane  = tid & 63;
    const int wave  = tid >> 6;
    const int b     = blockIdx.x;
    const float* __restrict__ um = umaps + (size_t)b * HH * WW;
    float* coords_out = out + PATCH_ELEMS;

    __shared__ float2 tvi[NT];       // (val, bitcast idx) per tile
    __shared__ int   boxes[NP][4];   // margin-expanded, clipped ex1,ex2,ey1,ey2
    __shared__ float rv[16];
    __shared__ int   ri[16];

    // ---- load own map's tile cache from K1 output (32KB, coalesced) --------
    {
        const float4* __restrict__ src = (const float4*)(tiles + (size_t)b * NT);
        float4* dst = (float4*)tvi;
        dst[tid]        = src[tid];
        dst[tid + 1024] = src[tid + 1024];
    }
    if (tid < NP) {   // boxes start empty => mask tests inert
        boxes[tid][0] = 0; boxes[tid][1] = 0; boxes[tid][2] = 0; boxes[tid][3] = 0;
    }
    __syncthreads();

    for (int k = 0; k < NP; ++k) {
        // block argmax over 4096 tile entries
        float bv = -INFINITY; int bi = 0x7fffffff;
        #pragma unroll
        for (int i = 0; i < 4; ++i) {
            const float2 e = tvi[tid + (i << 10)];
            const float v = e.x; const int x = __float_as_int(e.y);
            if (v > bv || (v == bv && x < bi)) { bv = v; bi = x; }
        }
        #pragma unroll
        for (int off = 32; off > 0; off >>= 1) {
            float ov = __shfl_down(bv, off);
            int   oi = __shfl_down(bi, off);
            if (ov > bv || (ov == bv && oi < bi)) { bv = ov; bi = oi; }
        }
        if (lane == 0) { rv[wave] = bv; ri[wave] = bi; }
        __syncthreads();

        if (tid == 0) {
            bv = rv[0]; bi = ri[0];
            #pragma unroll
            for (int w = 1; w < 16; ++w)
                if (rv[w] > bv || (rv[w] == bv && ri[w] < bi)) { bv = rv[w]; bi = ri[w]; }
            const int yc = bi >> 9, xc = bi & 511;
            int x1 = max(0, xc - HALF), x2 = min(WW, xc + HALF);
            int y1 = max(0, yc - HALF), y2 = min(HH, yc + HALF);
            if (x2 - x1 < EPS) { if (x1 == 0) x2 = EPS; else x1 = x2 - EPS; }
            if (y2 - y1 < EPS) { if (y1 == 0) y2 = EPS; else y1 = y2 - EPS; }
            boxes[k][0] = max(x1 - MARGIN, 0);
            boxes[k][1] = min(x2 + MARGIN, WW);
            boxes[k][2] = max(y1 - MARGIN, 0);
            boxes[k][3] = min(y2 + MARGIN, HH);

            const int o = (b * NP + k) * 4;
            coords_out[o + 0] = (float)x1;
            coords_out[o + 1] = (float)y1;
            coords_out[o + 2] = (float)x2;
            coords_out[o + 3] = (float)y2;
            sxy[b * NP + k] = make_int2(x1, y1);
        }
        __syncthreads();

        if (k == NP - 1) break;

        // ---- compacted rescan of tiles overlapping new box k ----
        const int ex1 = boxes[k][0], ex2 = boxes[k][1];
        const int ey1 = boxes[k][2], ey2 = boxes[k][3];
        const int tx1 = ex1 >> 3, tx2 = (ex2 - 1) >> 3;
        const int ty1 = ey1 >> 3, ty2 = (ey2 - 1) >> 3;
        const int wt  = tx2 - tx1 + 1;
        const int nt2 = wt * (ty2 - ty1 + 1);      // <= 625
        if (tid < nt2) {
            const int tx = tx1 + tid % wt;
            const int ty = ty1 + tid / wt;
            const int t  = (ty << 6) + tx;
            const int X1 = tx << 3, Y1 = ty << 3;
            if (X1 >= ex1 && X1 + 8 <= ex2 && Y1 >= ey1 && Y1 + 8 <= ey2) {
                tvi[t] = make_float2(-INFINITY, __int_as_float(0x7fffffff));
            } else {
                unsigned xm[NP]; int byl[NP], byh[NP];
                #pragma unroll
                for (int j = 0; j < NP; ++j) {
                    const int lo = min(max(boxes[j][0] - X1, 0), 8);
                    const int hi = min(max(boxes[j][1] - X1, 0), 8);
                    xm[j]  = (0xFFu << lo) & (0xFFu >> (8 - hi));
                    byl[j] = boxes[j][2]; byh[j] = boxes[j][3];
                }
                float nv = -INFINITY; int ni = 0x7fffffff;
                #pragma unroll
                for (int r = 0; r < 8; ++r) {
                    const int y = Y1 + r;
                    unsigned m8 = 0;
                    #pragma unroll
                    for (int j = 0; j < NP; ++j)
                        m8 |= (y >= byl[j] && y < byh[j]) ? xm[j] : 0u;
                    const int rowbase = y * WW + X1;
                    const float4 a = *(const float4*)(um + rowbase);
                    const float4 c = *(const float4*)(um + rowbase + 4);
                    const float vals[8] = {a.x, a.y, a.z, a.w, c.x, c.y, c.z, c.w};
                    #pragma unroll
                    for (int j2 = 0; j2 < 8; ++j2) {
                        if (!((m8 >> j2) & 1u) && vals[j2] > nv) { nv = vals[j2]; ni = rowbase + j2; }
                    }
                }
                tvi[t] = make_float2(nv, __int_as_float(ni));
            }
        }
        __syncthreads();
    }
}

// ============ K3: pure gather-copy extraction ===============================
// 512 blocks (b = blk>>4, slice = blk&15), 1024 thr, 3 float4 per thread.
__global__ __launch_bounds__(1024)
void extract_k(const float* __restrict__ images,
               const int2* __restrict__ sxy,
               float* __restrict__ out)
{
    const int tid   = threadIdx.x;
    const int b     = blockIdx.x >> 4;
    const int slice = blockIdx.x & (NSLICE - 1);
    float4* __restrict__ out4 = (float4*)out;

    #pragma unroll
    for (int it = 0; it < 3; ++it) {
        const int il  = slice * F4_PER_SLICE + (it << 10) + tid;  // within-map f4 idx
        const int nc  = il >> 12;            // (n,c) plane, 0..11
        const int n   = nc / 3;
        const int c   = nc - n * 3;
        const int py  = (il >> 5) & 127;
        const int px0 = (il & 31) << 2;

        const int2 xy = sxy[b * NP + n];
        const float* __restrict__ src =
            images + (((size_t)b * CH + c) * HH + (xy.y + py)) * WW + xy.x + px0;
        out4[(size_t)b * F4_PER_MAP + il] = make_float4(src[0], src[1], src[2], src[3]);
    }
}

extern "C" void kernel_launch(void* const* d_in, const int* in_sizes, int n_in,
                              void* d_out, int out_size, void* d_ws, size_t ws_size,
                              hipStream_t stream) {
    const float* images = (const float*)d_in[0];
    const float* umaps  = (const float*)d_in[1];
    float* out          = (float*)d_out;
    float2* tiles       = (float2*)d_ws;                                // 1 MB
    int2*   sxy         = (int2*)((char*)d_ws + (size_t)BN * NT * sizeof(float2));

    tile_scan<<<K1_NBLK, K1_NTHR, 0, stream>>>(umaps, tiles);
    select_k<<<BN, 1024, 0, stream>>>(umaps, tiles, out, sxy);
    extract_k<<<EX_NBLK, 1024, 0, stream>>>(images, sxy, out);
}

// Round 3
// 180.433 us; speedup vs baseline: 1.2940x; 1.0433x over previous
//
#include <hip/hip_runtime.h>
#include <math.h>
#include <float.h>

#define BN 32
#define CH 3
#define HH 512
#define WW 512
#define NP 4
#define EPS 128
#define HALF 64
#define MARGIN 32

#define NT 4096                                  // 64x64 grid of 8x8 tiles per map
#define PATCH_ELEMS (BN * NP * CH * EPS * EPS)   // 6291456
#define F4_PER_MAP (NP * CH * EPS * EPS / 4)     // 49152 (12 planes * 4096 f4)
#define NSLICE 16
#define F4_PER_SLICE (F4_PER_MAP / NSLICE)       // 3072
#define K1_NTHR 256
#define K1_NBLK (BN * NT / K1_NTHR)              // 512
#define EX_NBLK (BN * NSLICE)                    // 512

// ============ K1: per-tile (max,argmax) for all maps, computed ONCE =========
__global__ __launch_bounds__(K1_NTHR)
void tile_scan(const float* __restrict__ umaps, float2* __restrict__ tiles)
{
    const int g  = blockIdx.x * K1_NTHR + threadIdx.x;
    const int b  = g >> 12;                      // map
    const int t  = g & (NT - 1);                 // tile within map
    const int tx = t & 63, ty = t >> 6;
    const float* __restrict__ um = umaps + (size_t)b * HH * WW;
    const int x0 = tx << 3, y0 = ty << 3;
    float bv = -INFINITY; int bi = 0x7fffffff;
    #pragma unroll
    for (int r = 0; r < 8; ++r) {
        const int rowbase = (y0 + r) * WW + x0;
        const float4 a = *(const float4*)(um + rowbase);
        const float4 c = *(const float4*)(um + rowbase + 4);
        if (a.x > bv) { bv = a.x; bi = rowbase + 0; }
        if (a.y > bv) { bv = a.y; bi = rowbase + 1; }
        if (a.z > bv) { bv = a.z; bi = rowbase + 2; }
        if (a.w > bv) { bv = a.w; bi = rowbase + 3; }
        if (c.x > bv) { bv = c.x; bi = rowbase + 4; }
        if (c.y > bv) { bv = c.y; bi = rowbase + 5; }
        if (c.z > bv) { bv = c.z; bi = rowbase + 6; }
        if (c.w > bv) { bv = c.w; bi = rowbase + 7; }
    }
    tiles[g] = make_float2(bv, __int_as_float(bi));
}

// ============ K2: greedy selection, ONCE per map, lazy dirty re-eval ========
// level2[64] = per-tile-row (max, argmax): whole-map argmax is a single-wave
// reduce. Boxes only invalidate lazily: fully-covered tiles -> -inf (free),
// perimeter tiles -> dirty bit; a dirty winner gets recomputed (64 px) by
// wave 0 only. Stale values are upper bounds => clean winner is exact.
__global__ __launch_bounds__(1024)
void select_k(const float* __restrict__ umaps,
              const float2* __restrict__ tiles,
              float* __restrict__ out,
              int2* __restrict__ sxy)
{
    const int tid  = threadIdx.x;
    const int lane = tid & 63;
    const int wave = tid >> 6;
    const int b    = blockIdx.x;
    const float* __restrict__ um = umaps + (size_t)b * HH * WW;
    float* coords_out = out + PATCH_ELEMS;

    __shared__ float2   tvi[NT];      // (val, bitcast pixel idx) per tile
    __shared__ float2   l2[64];       // per-tile-row (val, bitcast pixel idx)
    __shared__ unsigned dirty[128];   // 4096 dirty bits
    __shared__ int      boxes[NP][4]; // margin-expanded ex1,ex2,ey1,ey2

    // ---- load tile cache (32KB, coalesced) + init ---------------------------
    {
        const float4* __restrict__ src = (const float4*)(tiles + (size_t)b * NT);
        float4* dst = (float4*)tvi;
        dst[tid]        = src[tid];
        dst[tid + 1024] = src[tid + 1024];
    }
    if (tid < 128) dirty[tid] = 0u;
    if (tid < NP) { boxes[tid][0] = 0; boxes[tid][1] = 0; boxes[tid][2] = 0; boxes[tid][3] = 0; }
    __syncthreads();

    // ---- build level2: 16 waves x 4 rows ------------------------------------
    for (int r = wave; r < 64; r += 16) {
        const float2 e = tvi[(r << 6) + lane];
        float v = e.x; int ix = __float_as_int(e.y);
        #pragma unroll
        for (int off = 32; off > 0; off >>= 1) {
            const float ov = __shfl_down(v, off);
            const int   oi = __shfl_down(ix, off);
            if (ov > v || (ov == v && oi < ix)) { v = ov; ix = oi; }
        }
        if (lane == 0) l2[r] = make_float2(v, __int_as_float(ix));
    }
    __syncthreads();

    for (int k = 0; k < NP; ++k) {
        // ---- wave-0-only accept loop (no block barriers inside) -------------
        if (wave == 0) {
            for (;;) {
                // whole-map argmax from level2 (64 entries)
                const float2 e = l2[lane];
                float v = e.x; int ix = __float_as_int(e.y);
                #pragma unroll
                for (int off = 32; off > 0; off >>= 1) {
                    const float ov = __shfl_down(v, off);
                    const int   oi = __shfl_down(ix, off);
                    if (ov > v || (ov == v && oi < ix)) { v = ov; ix = oi; }
                }
                ix = __shfl(ix, 0);                       // broadcast winner px idx
                const int t = ((ix >> 12) << 6) | ((ix & 511) >> 3);
                const bool isdirty = (dirty[t >> 5] >> (t & 31)) & 1u;
                if (!isdirty) {
                    if (lane == 0) {
                        const int yc = ix >> 9, xc = ix & 511;
                        int x1 = max(0, xc - HALF), x2 = min(WW, xc + HALF);
                        int y1 = max(0, yc - HALF), y2 = min(HH, yc + HALF);
                        if (x2 - x1 < EPS) { if (x1 == 0) x2 = EPS; else x1 = x2 - EPS; }
                        if (y2 - y1 < EPS) { if (y1 == 0) y2 = EPS; else y1 = y2 - EPS; }
                        boxes[k][0] = max(x1 - MARGIN, 0);
                        boxes[k][1] = min(x2 + MARGIN, WW);
                        boxes[k][2] = max(y1 - MARGIN, 0);
                        boxes[k][3] = min(y2 + MARGIN, HH);
                        const int o = (b * NP + k) * 4;
                        coords_out[o + 0] = (float)x1;
                        coords_out[o + 1] = (float)y1;
                        coords_out[o + 2] = (float)x2;
                        coords_out[o + 3] = (float)y2;
                        sxy[b * NP + k] = make_int2(x1, y1);
                    }
                    break;
                }
                // ---- recompute dirty tile t: 1 px per lane ------------------
                const int ty = t >> 6, tx = t & 63;
                const int y = (ty << 3) + (lane >> 3), x = (tx << 3) + (lane & 7);
                float pv = um[y * WW + x];
                int   pi = y * WW + x;
                bool m = false;
                #pragma unroll
                for (int j = 0; j < NP; ++j)
                    m |= (y >= boxes[j][2] && y < boxes[j][3] &&
                          x >= boxes[j][0] && x < boxes[j][1]);
                if (m) { pv = -INFINITY; pi = 0x7fffffff; }
                float nv = pv; int ni = pi;
                #pragma unroll
                for (int off = 32; off > 0; off >>= 1) {
                    const float ov = __shfl_down(nv, off);
                    const int   oi = __shfl_down(ni, off);
                    if (ov > nv || (ov == nv && oi < ni)) { nv = ov; ni = oi; }
                }
                nv = __shfl(nv, 0); ni = __shfl(ni, 0);
                if (lane == 0) {
                    tvi[t] = make_float2(nv, __int_as_float(ni));
                    dirty[t >> 5] &= ~(1u << (t & 31));
                }
                // repair level2 row ty (substitute new value in-register)
                const float2 e2 = tvi[(ty << 6) + lane];
                float rv; int ri;
                if (lane == tx) { rv = nv; ri = ni; }
                else            { rv = e2.x; ri = __float_as_int(e2.y); }
                #pragma unroll
                for (int off = 32; off > 0; off >>= 1) {
                    const float ov = __shfl_down(rv, off);
                    const int   oi = __shfl_down(ri, off);
                    if (ov > rv || (ov == rv && oi < ri)) { rv = ov; ri = oi; }
                }
                if (lane == 0) l2[ty] = make_float2(rv, __int_as_float(ri));
            }
        }
        __syncthreads();

        if (k == NP - 1) break;

        // ---- eager cheap invalidation for new box k -------------------------
        const int ex1 = boxes[k][0], ex2 = boxes[k][1];
        const int ey1 = boxes[k][2], ey2 = boxes[k][3];
        const int tx1 = ex1 >> 3, tx2 = (ex2 - 1) >> 3;
        const int ty1 = ey1 >> 3, ty2 = (ey2 - 1) >> 3;
        const int wt  = tx2 - tx1 + 1;
        const int nt2 = wt * (ty2 - ty1 + 1);      // <= 625
        if (tid < nt2) {
            const int tx = tx1 + tid % wt;
            const int ty = ty1 + tid / wt;
            const int t  = (ty << 6) + tx;
            const int X1 = tx << 3, Y1 = ty << 3;
            if (X1 >= ex1 && X1 + 8 <= ex2 && Y1 >= ey1 && Y1 + 8 <= ey2)
                tvi[t] = make_float2(-INFINITY, __int_as_float(0x7fffffff));
            else
                atomicOr(&dirty[t >> 5], 1u << (t & 31));
        }
        __syncthreads();

        // ---- repair level2 for affected rows --------------------------------
        for (int r = ty1 + wave; r <= ty2; r += 16) {
            const float2 e = tvi[(r << 6) + lane];
            float v = e.x; int ix = __float_as_int(e.y);
            #pragma unroll
            for (int off = 32; off > 0; off >>= 1) {
                const float ov = __shfl_down(v, off);
                const int   oi = __shfl_down(ix, off);
                if (ov > v || (ov == v && oi < ix)) { v = ov; ix = oi; }
            }
            if (lane == 0) l2[r] = make_float2(v, __int_as_float(ix));
        }
        __syncthreads();
    }
}

// ============ K3: pure gather-copy extraction ===============================
__global__ __launch_bounds__(1024)
void extract_k(const float* __restrict__ images,
               const int2* __restrict__ sxy,
               float* __restrict__ out)
{
    const int tid   = threadIdx.x;
    const int b     = blockIdx.x >> 4;
    const int slice = blockIdx.x & (NSLICE - 1);
    float4* __restrict__ out4 = (float4*)out;

    #pragma unroll
    for (int it = 0; it < 3; ++it) {
        const int il  = slice * F4_PER_SLICE + (it << 10) + tid;  // within-map f4 idx
        const int nc  = il >> 12;            // (n,c) plane, 0..11
        const int n   = nc / 3;
        const int c   = nc - n * 3;
        const int py  = (il >> 5) & 127;
        const int px0 = (il & 31) << 2;

        const int2 xy = sxy[b * NP + n];
        const float* __restrict__ src =
            images + (((size_t)b * CH + c) * HH + (xy.y + py)) * WW + xy.x + px0;
        out4[(size_t)b * F4_PER_MAP + il] = make_float4(src[0], src[1], src[2], src[3]);
    }
}

extern "C" void kernel_launch(void* const* d_in, const int* in_sizes, int n_in,
                              void* d_out, int out_size, void* d_ws, size_t ws_size,
                              hipStream_t stream) {
    const float* images = (const float*)d_in[0];
    const float* umaps  = (const float*)d_in[1];
    float* out          = (float*)d_out;
    float2* tiles       = (float2*)d_ws;                                // 1 MB
    int2*   sxy         = (int2*)((char*)d_ws + (size_t)BN * NT * sizeof(float2));

    tile_scan<<<K1_NBLK, K1_NTHR, 0, stream>>>(umaps, tiles);
    select_k<<<BN, 1024, 0, stream>>>(umaps, tiles, out, sxy);
    extract_k<<<EX_NBLK, 1024, 0, stream>>>(images, sxy, out);
}

// Round 4
// 173.783 us; speedup vs baseline: 1.3436x; 1.0383x over previous
//
#include <hip/hip_runtime.h>
#include <math.h>
#include <float.h>

#define BN 32
#define CH 3
#define HH 512
#define WW 512
#define NP 4
#define EPS 128
#define HALF 64
#define MARGIN 32

#define NT 4096                                  // 64x64 grid of 8x8 tiles per map
#define PATCH_ELEMS (BN * NP * CH * EPS * EPS)   // 6291456
#define F4_PER_MAP (NP * CH * EPS * EPS / 4)     // 49152 (12 planes * 4096 f4)
#define NSLICE 16
#define F4_PER_SLICE (F4_PER_MAP / NSLICE)       // 3072
#define K1_NTHR 256
#define K1_NBLK (BN * NT / K1_NTHR)              // 512

// ============ K1: per-tile (max,argmax) for all maps, computed ONCE =========
__global__ __launch_bounds__(K1_NTHR)
void tile_scan(const float* __restrict__ umaps, float2* __restrict__ tiles)
{
    const int g  = blockIdx.x * K1_NTHR + threadIdx.x;
    const int b  = g >> 12;                      // map
    const int t  = g & (NT - 1);                 // tile within map
    const int tx = t & 63, ty = t >> 6;
    const float* __restrict__ um = umaps + (size_t)b * HH * WW;
    const int x0 = tx << 3, y0 = ty << 3;
    float bv = -INFINITY; int bi = 0x7fffffff;
    #pragma unroll
    for (int r = 0; r < 8; ++r) {
        const int rowbase = (y0 + r) * WW + x0;
        const float4 a = *(const float4*)(um + rowbase);
        const float4 c = *(const float4*)(um + rowbase + 4);
        if (a.x > bv) { bv = a.x; bi = rowbase + 0; }
        if (a.y > bv) { bv = a.y; bi = rowbase + 1; }
        if (a.z > bv) { bv = a.z; bi = rowbase + 2; }
        if (a.w > bv) { bv = a.w; bi = rowbase + 3; }
        if (c.x > bv) { bv = c.x; bi = rowbase + 4; }
        if (c.y > bv) { bv = c.y; bi = rowbase + 5; }
        if (c.z > bv) { bv = c.z; bi = rowbase + 6; }
        if (c.w > bv) { bv = c.w; bi = rowbase + 7; }
    }
    tiles[g] = make_float2(bv, __int_as_float(bi));
}

// ============ K2: fused redundant lazy selection + slice extraction =========
// 512 blocks: b = blk&31 (XCD spread), slice = blk>>5. Each slice needs ONLY
// patch n = slice>>2 => break out of the greedy loop as soon as that box is
// accepted; early classes start extracting while others still select.
// Deterministic selection => all blocks of a map agree. slice 15 (full chain)
// writes coords.
__global__ __launch_bounds__(1024)
void select_extract(const float* __restrict__ images,
                    const float* __restrict__ umaps,
                    const float2* __restrict__ tiles,
                    float* __restrict__ out)
{
    const int tid   = threadIdx.x;
    const int lane  = tid & 63;
    const int wave  = tid >> 6;
    const int b     = blockIdx.x & (BN - 1);
    const int slice = blockIdx.x >> 5;
    const int nwant = slice >> 2;                 // the one patch this block extracts
    const float* __restrict__ um = umaps + (size_t)b * HH * WW;
    float* coords_out = out + PATCH_ELEMS;

    __shared__ float2   tvi[NT];      // (val, bitcast pixel idx) per tile
    __shared__ float2   l2[64];       // per-tile-row (val, bitcast pixel idx)
    __shared__ unsigned dirty[128];   // 4096 dirty bits
    __shared__ int      boxes[NP][4]; // margin-expanded ex1,ex2,ey1,ey2
    __shared__ int      px1, py1;     // accepted (x1,y1) for patch nwant

    // ---- load tile cache (32KB, coalesced) + init ---------------------------
    {
        const float4* __restrict__ src = (const float4*)(tiles + (size_t)b * NT);
        float4* dst = (float4*)tvi;
        dst[tid]        = src[tid];
        dst[tid + 1024] = src[tid + 1024];
    }
    if (tid < 128) dirty[tid] = 0u;
    if (tid < NP) { boxes[tid][0] = 0; boxes[tid][1] = 0; boxes[tid][2] = 0; boxes[tid][3] = 0; }
    __syncthreads();

    // ---- build level2: 16 waves x 4 rows ------------------------------------
    for (int r = wave; r < 64; r += 16) {
        const float2 e = tvi[(r << 6) + lane];
        float v = e.x; int ix = __float_as_int(e.y);
        #pragma unroll
        for (int off = 32; off > 0; off >>= 1) {
            const float ov = __shfl_down(v, off);
            const int   oi = __shfl_down(ix, off);
            if (ov > v || (ov == v && oi < ix)) { v = ov; ix = oi; }
        }
        if (lane == 0) l2[r] = make_float2(v, __int_as_float(ix));
    }
    __syncthreads();

    for (int k = 0; k <= nwant; ++k) {
        // ---- wave-0-only accept loop (no block barriers inside) -------------
        if (wave == 0) {
            for (;;) {
                const float2 e = l2[lane];
                float v = e.x; int ix = __float_as_int(e.y);
                #pragma unroll
                for (int off = 32; off > 0; off >>= 1) {
                    const float ov = __shfl_down(v, off);
                    const int   oi = __shfl_down(ix, off);
                    if (ov > v || (ov == v && oi < ix)) { v = ov; ix = oi; }
                }
                ix = __shfl(ix, 0);                       // broadcast winner px idx
                const int t = ((ix >> 12) << 6) | ((ix & 511) >> 3);
                const bool isdirty = (dirty[t >> 5] >> (t & 31)) & 1u;
                if (!isdirty) {
                    if (lane == 0) {
                        const int yc = ix >> 9, xc = ix & 511;
                        int x1 = max(0, xc - HALF), x2 = min(WW, xc + HALF);
                        int y1 = max(0, yc - HALF), y2 = min(HH, yc + HALF);
                        if (x2 - x1 < EPS) { if (x1 == 0) x2 = EPS; else x1 = x2 - EPS; }
                        if (y2 - y1 < EPS) { if (y1 == 0) y2 = EPS; else y1 = y2 - EPS; }
                        boxes[k][0] = max(x1 - MARGIN, 0);
                        boxes[k][1] = min(x2 + MARGIN, WW);
                        boxes[k][2] = max(y1 - MARGIN, 0);
                        boxes[k][3] = min(y2 + MARGIN, HH);
                        if (k == nwant) { px1 = x1; py1 = y1; }
                        if (slice == NSLICE - 1) {        // one coord writer per map
                            const int o = (b * NP + k) * 4;
                            coords_out[o + 0] = (float)x1;
                            coords_out[o + 1] = (float)y1;
                            coords_out[o + 2] = (float)x2;
                            coords_out[o + 3] = (float)y2;
                        }
                    }
                    break;
                }
                // ---- recompute dirty tile t: 1 px per lane ------------------
                const int ty = t >> 6, tx = t & 63;
                const int y = (ty << 3) + (lane >> 3), x = (tx << 3) + (lane & 7);
                float pv = um[y * WW + x];
                int   pi = y * WW + x;
                bool m = false;
                #pragma unroll
                for (int j = 0; j < NP; ++j)
                    m |= (y >= boxes[j][2] && y < boxes[j][3] &&
                          x >= boxes[j][0] && x < boxes[j][1]);
                if (m) { pv = -INFINITY; pi = 0x7fffffff; }
                float nv = pv; int ni = pi;
                #pragma unroll
                for (int off = 32; off > 0; off >>= 1) {
                    const float ov = __shfl_down(nv, off);
                    const int   oi = __shfl_down(ni, off);
                    if (ov > nv || (ov == nv && oi < ni)) { nv = ov; ni = oi; }
                }
                nv = __shfl(nv, 0); ni = __shfl(ni, 0);
                if (lane == 0) {
                    tvi[t] = make_float2(nv, __int_as_float(ni));
                    dirty[t >> 5] &= ~(1u << (t & 31));
                }
                // repair level2 row ty (substitute new value in-register)
                const float2 e2 = tvi[(ty << 6) + lane];
                float rv; int ri;
                if (lane == tx) { rv = nv; ri = ni; }
                else            { rv = e2.x; ri = __float_as_int(e2.y); }
                #pragma unroll
                for (int off = 32; off > 0; off >>= 1) {
                    const float ov = __shfl_down(rv, off);
                    const int   oi = __shfl_down(ri, off);
                    if (ov > rv || (ov == rv && oi < ri)) { rv = ov; ri = oi; }
                }
                if (lane == 0) l2[ty] = make_float2(rv, __int_as_float(ri));
            }
        }
        __syncthreads();

        if (k == nwant) break;     // this block has its box; go extract

        // ---- eager cheap invalidation for new box k -------------------------
        const int ex1 = boxes[k][0], ex2 = boxes[k][1];
        const int ey1 = boxes[k][2], ey2 = boxes[k][3];
        const int tx1 = ex1 >> 3, tx2 = (ex2 - 1) >> 3;
        const int ty1 = ey1 >> 3, ty2 = (ey2 - 1) >> 3;
        const int wt  = tx2 - tx1 + 1;
        const int nt2 = wt * (ty2 - ty1 + 1);      // <= 625
        if (tid < nt2) {
            const int tx = tx1 + tid % wt;
            const int ty = ty1 + tid / wt;
            const int t  = (ty << 6) + tx;
            const int X1 = tx << 3, Y1 = ty << 3;
            if (X1 >= ex1 && X1 + 8 <= ex2 && Y1 >= ey1 && Y1 + 8 <= ey2)
                tvi[t] = make_float2(-INFINITY, __int_as_float(0x7fffffff));
            else
                atomicOr(&dirty[t >> 5], 1u << (t & 31));
        }
        __syncthreads();

        // ---- repair level2 for affected rows --------------------------------
        for (int r = ty1 + wave; r <= ty2; r += 16) {
            const float2 e = tvi[(r << 6) + lane];
            float v = e.x; int ix = __float_as_int(e.y);
            #pragma unroll
            for (int off = 32; off > 0; off >>= 1) {
                const float ov = __shfl_down(v, off);
                const int   oi = __shfl_down(ix, off);
                if (ov > v || (ov == v && oi < ix)) { v = ov; ix = oi; }
            }
            if (lane == 0) l2[r] = make_float2(v, __int_as_float(ix));
        }
        __syncthreads();
    }

    // ---- extraction: own map's 1/16 slice (single patch n = nwant) ----------
    const int x1 = px1, y1 = py1;
    float4* __restrict__ out4 = (float4*)out;
    #pragma unroll
    for (int it = 0; it < 3; ++it) {
        const int il  = slice * F4_PER_SLICE + (it << 10) + tid;  // within-map f4 idx
        const int nc  = il >> 12;            // (n,c) plane; n == nwant by construction
        const int c   = nc - nwant * 3;
        const int py  = (il >> 5) & 127;
        const int px0 = (il & 31) << 2;

        const float* __restrict__ src =
            images + (((size_t)b * CH + c) * HH + (y1 + py)) * WW + x1 + px0;
        out4[(size_t)b * F4_PER_MAP + il] = make_float4(src[0], src[1], src[2], src[3]);
    }
}

extern "C" void kernel_launch(void* const* d_in, const int* in_sizes, int n_in,
                              void* d_out, int out_size, void* d_ws, size_t ws_size,
                              hipStream_t stream) {
    const float* images = (const float*)d_in[0];
    const float* umaps  = (const float*)d_in[1];
    float* out          = (float*)d_out;
    float2* tiles       = (float2*)d_ws;        // 32 maps * 4096 tiles * 8B = 1MB

    tile_scan<<<K1_NBLK, K1_NTHR, 0, stream>>>(umaps, tiles);
    select_extract<<<BN * NSLICE, 1024, 0, stream>>>(images, umaps, tiles, out);
}